// Round 15
// baseline (155.493 us; speedup 1.0000x reference)
//
#include <hip/hip_runtime.h>

#define HORIZON 28
#define GAMMA 0.1f

typedef __attribute__((ext_vector_type(8))) _Float16 half8;   // MFMA A/B frag (4 VGPR)
typedef __attribute__((ext_vector_type(2))) _Float16 half2t;
typedef __attribute__((ext_vector_type(4))) float f32x4;      // MFMA C/D frag
typedef __attribute__((ext_vector_type(4))) unsigned int u32x4;

// guaranteed-packed fp16 ops (VOP3P), register-only so the scheduler can move them
__device__ __forceinline__ unsigned pk_fma(unsigned a, unsigned b, unsigned c) {
    unsigned d;
    asm("v_pk_fma_f16 %0, %1, %2, %3" : "=v"(d) : "v"(a), "v"(b), "v"(c));
    return d;
}
__device__ __forceinline__ unsigned pk_max(unsigned a, unsigned b) {
    unsigned d;
    asm("v_pk_max_f16 %0, %1, %2" : "=v"(d) : "v"(a), "v"(b));
    return d;
}
__device__ __forceinline__ unsigned splat_lo(unsigned x) {   // {x.lo, x.lo}
    return __builtin_amdgcn_perm(x, x, 0x05040504u);
}
__device__ __forceinline__ unsigned splat_hi(unsigned x) {   // {x.hi, x.hi}
    return __builtin_amdgcn_perm(x, x, 0x07060706u);
}

__global__ void __launch_bounds__(256) sir_kernel(
    const float* __restrict__ inputs,
    const float* __restrict__ W1,
    const float* __restrict__ b1,
    const float* __restrict__ W2,
    const float* __restrict__ b2,
    const float* __restrict__ W3,
    const float* __restrict__ b3,
    float* __restrict__ out,
    int nrows)
{
    __shared__ float sWs[32], sWi[32], sWr[32], sWb[32];       // W1 SoA + b1 (staging)
    __shared__ unsigned sOutP[4][64 * 15];   // per-wave fp16 output staging, stride 15 (pad)

    const int tid  = threadIdx.x;
    const int lane = tid & 63;
    const int wid  = tid >> 6;
    const int g    = lane >> 4;    // lane group = k-chunk (k = 8g..8g+7); own tile = g
    const int c15  = lane & 15;    // MFMA col = data row within a 16-row tile

    if (tid < 32) {
        sWs[tid] = W1[tid];
        sWi[tid] = W1[32 + tid];
        sWr[tid] = W1[64 + tid];
        sWb[tid] = b1[tid];
    }
    __syncthreads();

    // This lane's 8 W1 columns as packed fp16 even/odd pairs (RNE, setup-only)
    unsigned wps[4], wpi[4], wpr[4], wpb[4];
    #pragma unroll
    for (int p = 0; p < 4; ++p) {
        const int k0 = g*8 + 2*p;
        half2t a, b, c, d;
        a[0] = (_Float16)sWs[k0]; a[1] = (_Float16)sWs[k0+1];
        b[0] = (_Float16)sWi[k0]; b[1] = (_Float16)sWi[k0+1];
        c[0] = (_Float16)sWr[k0]; c[1] = (_Float16)sWr[k0+1];
        d[0] = (_Float16)sWb[k0]; d[1] = (_Float16)sWb[k0+1];
        wps[p] = __builtin_bit_cast(unsigned, a);
        wpi[p] = __builtin_bit_cast(unsigned, b);
        wpr[p] = __builtin_bit_cast(unsigned, c);
        wpb[p] = __builtin_bit_cast(unsigned, d);
    }

    // Persistent A-frags: W2 fp16 hi + lo residual. lane: A[out=c15][k=8g+j] = W2[k][c15]
    half8 ahi, alo;
    {
        u32x4 uh, ul;
        #pragma unroll
        for (int jj = 0; jj < 4; ++jj) {
            const float we = W2[(g*8 + 2*jj    )*16 + c15];
            const float wo = W2[(g*8 + 2*jj + 1)*16 + c15];
            half2t hh; hh[0] = (_Float16)we; hh[1] = (_Float16)wo;       // RNE
            half2t hl; hl[0] = (_Float16)(we - (float)hh[0]);
            hl[1] = (_Float16)(wo - (float)hh[1]);
            uh[jj] = __builtin_bit_cast(unsigned, hh);
            ul[jj] = __builtin_bit_cast(unsigned, hl);
        }
        ahi = __builtin_bit_cast(half8, uh);
        alo = __builtin_bit_cast(half8, ul);
    }
    const f32x4 b2f = *reinterpret_cast<const f32x4*>(b2 + g*4);   // C-init
    const f32x4 w3f = *reinterpret_cast<const f32x4*>(W3 + g*4);   // outs 4g..4g+3
    const float b3v = b3[0];

    const int row = blockIdx.x * 256 + tid;
    if (row >= nrows) return;   // never taken at B=2^20 (wave stays intact)

    const float* p = inputs + ((long)row * 8 + 7) * 3;
    float s  = p[0];
    float iv = p[1];
    float r  = p[2];
    const float rcpN = 1.0f / (s + iv + r);   // N conserved by SIR update

    // bpermute byte-addresses: tile m pulls from lane 16m + c15 (per-lane constant)
    const int adr0 = (c15     ) << 2;
    const int adr1 = (c15 + 16) << 2;
    const int adr2 = (c15 + 32) << 2;
    const int adr3 = (c15 + 48) << 2;

    // one tile: packed-fp16 L1 from state words {s,i} and {r,r}, 2 MFMA, L3 partial
    auto tile = [&](int wsi, int wr) -> float {
        const unsigned svw = splat_lo((unsigned)wsi);   // {s, s}
        const unsigned vvw = splat_hi((unsigned)wsi);   // {i, i}
        const unsigned rvw = (unsigned)wr;              // already {r, r}
        u32x4 ub;
        #pragma unroll
        for (int pp = 0; pp < 4; ++pp) {
            unsigned h = pk_fma(svw, wps[pp], wpb[pp]);
            h = pk_fma(vvw, wpi[pp], h);
            h = pk_fma(rvw, wpr[pp], h);
            h = pk_max(h, 0u);
            ub[pp] = h;   // this IS the B-frag word {h1[k even], h1[k odd]}
        }
        const half8 bh = __builtin_bit_cast(half8, ub);
        f32x4 acc = __builtin_amdgcn_mfma_f32_16x16x32_f16(ahi, bh, b2f, 0, 0, 0);
        acc = __builtin_amdgcn_mfma_f32_16x16x32_f16(alo, bh, acc, 0, 0, 0);
        float pz = fmaxf(acc[0], 0.0f) * w3f[0];
        pz = fmaf(fmaxf(acc[1], 0.0f), w3f[1], pz);
        pz = fmaf(fmaxf(acc[2], 0.0f), w3f[2], pz);
        pz = fmaf(fmaxf(acc[3], 0.0f), w3f[3], pz);
        return pz;
    };

    auto step = [&]() -> float {
        // publish state as 2 packed-fp16 words; register gather via ds_bpermute
        const int usi = __builtin_bit_cast(int, __builtin_amdgcn_cvt_pkrtz(s, iv));
        const int ur  = __builtin_bit_cast(int, __builtin_amdgcn_cvt_pkrtz(r, r));

        float z[4];
        {
            const int w0 = __builtin_amdgcn_ds_bpermute(adr0, usi);
            const int x0 = __builtin_amdgcn_ds_bpermute(adr0, ur);
            float pz = tile(w0, x0);
            pz += __shfl_xor(pz, 16, 64);
            pz += __shfl_xor(pz, 32, 64);
            z[0] = pz;
        }
        {
            const int w1 = __builtin_amdgcn_ds_bpermute(adr1, usi);
            const int x1 = __builtin_amdgcn_ds_bpermute(adr1, ur);
            float pz = tile(w1, x1);
            pz += __shfl_xor(pz, 16, 64);
            pz += __shfl_xor(pz, 32, 64);
            z[1] = pz;
        }
        {
            const int w2 = __builtin_amdgcn_ds_bpermute(adr2, usi);
            const int x2 = __builtin_amdgcn_ds_bpermute(adr2, ur);
            float pz = tile(w2, x2);
            pz += __shfl_xor(pz, 16, 64);
            pz += __shfl_xor(pz, 32, 64);
            z[2] = pz;
        }
        {
            const int w3v = __builtin_amdgcn_ds_bpermute(adr3, usi);
            const int x3 = __builtin_amdgcn_ds_bpermute(adr3, ur);
            float pz = tile(w3v, x3);
            pz += __shfl_xor(pz, 16, 64);
            pz += __shfl_xor(pz, 32, 64);
            z[3] = pz;
        }
        // my row = 16g + c15 -> z from tile m == g
        const float zz = (g == 0) ? z[0] : (g == 1) ? z[1] : (g == 2) ? z[2] : z[3];
        const float zb = zz + b3v;

        // softplus (stable): max(z,0) + ln2*log2(1 + exp2(-|z|*log2e))
        const float t = __builtin_amdgcn_exp2f(-fabsf(zb) * 1.44269504088896341f);
        const float beta = fmaxf(zb, 0.0f) + 0.69314718055994531f * __builtin_amdgcn_logf(1.0f + t);
        const float new_inf = beta * s * iv * rcpN;
        const float new_rec = GAMMA * iv;
        s  = s - new_inf;
        iv = iv + new_inf - new_rec;
        r  = r + new_rec;
        return iv;
    };

    // 28 steps; stage outputs as packed fp16 into padded [64][15]-dword layout
    unsigned* const sOutW = &sOutP[wid][0];
    #pragma unroll 1
    for (int tt = 0; tt < 7; ++tt) {
        const float o0 = step();
        const float o1 = step();
        const float o2 = step();
        const float o3 = step();
        const unsigned pk0 = __builtin_bit_cast(unsigned, __builtin_amdgcn_cvt_pkrtz(o0, o1));
        const unsigned pk1 = __builtin_bit_cast(unsigned, __builtin_amdgcn_cvt_pkrtz(o2, o3));
        sOutW[lane * 15 + 2*tt]     = pk0;
        sOutW[lane * 15 + 2*tt + 1] = pk1;
    }

    // coalesced writeback: wave's 64 rows = 1792 contiguous floats in `out`
    const long gbase = (long)(blockIdx.x * 256 + wid * 64) * HORIZON;
    #pragma unroll
    for (int t = 0; t < 7; ++t) {
        const int e4 = t * 256 + lane * 4;   // float index within wave block (mult of 4)
        const int rr = e4 / 28;              // row; 28 % 4 == 0 -> float4 never crosses rows
        const int cc = e4 % 28;              // 0,4,...,24
        const unsigned d0 = sOutW[rr * 15 + (cc >> 1)];
        const unsigned d1 = sOutW[rr * 15 + (cc >> 1) + 1];
        const half2t h0 = __builtin_bit_cast(half2t, d0);
        const half2t h1 = __builtin_bit_cast(half2t, d1);
        f32x4 v;
        v[0] = (float)h0[0]; v[1] = (float)h0[1];
        v[2] = (float)h1[0]; v[3] = (float)h1[1];
        *reinterpret_cast<f32x4*>(out + gbase + e4) = v;
    }
}

extern "C" void kernel_launch(void* const* d_in, const int* in_sizes, int n_in,
                              void* d_out, int out_size, void* d_ws, size_t ws_size,
                              hipStream_t stream) {
    const float* inputs = (const float*)d_in[0];
    const float* W1 = (const float*)d_in[1];
    const float* b1 = (const float*)d_in[2];
    const float* W2 = (const float*)d_in[3];
    const float* b2 = (const float*)d_in[4];
    const float* W3 = (const float*)d_in[5];
    const float* b3 = (const float*)d_in[6];
    float* out = (float*)d_out;

    const int nrows = in_sizes[0] / 24;   // (B, 8, 3) fp32
    const int grid = (nrows + 255) / 256;
    sir_kernel<<<grid, 256, 0, stream>>>(inputs, W1, b1, W2, b2, W3, b3, out, nrows);
}

// Round 18
// 150.524 us; speedup vs baseline: 1.0330x; 1.0330x over previous
//
#include <hip/hip_runtime.h>

#define HORIZON 28
#define GAMMA 0.1f

typedef __attribute__((ext_vector_type(8))) _Float16 half8;   // MFMA A/B frag (4 VGPR)
typedef __attribute__((ext_vector_type(2))) _Float16 half2t;
typedef __attribute__((ext_vector_type(4))) float f32x4;      // MFMA C/D frag
typedef __attribute__((ext_vector_type(4))) unsigned int u32x4;

// guaranteed-packed fp16 ops (VOP3P), register-only so the scheduler can move them
__device__ __forceinline__ unsigned pk_fma(unsigned a, unsigned b, unsigned c) {
    unsigned d;
    asm("v_pk_fma_f16 %0, %1, %2, %3" : "=v"(d) : "v"(a), "v"(b), "v"(c));
    return d;
}
__device__ __forceinline__ unsigned pk_max(unsigned a, unsigned b) {
    unsigned d;
    asm("v_pk_max_f16 %0, %1, %2" : "=v"(d) : "v"(a), "v"(b));
    return d;
}

__global__ void __launch_bounds__(256) sir_kernel(
    const float* __restrict__ inputs,
    const float* __restrict__ W1,
    const float* __restrict__ b1,
    const float* __restrict__ W2,
    const float* __restrict__ b2,
    const float* __restrict__ W3,
    const float* __restrict__ b3,
    float* __restrict__ out,
    int nrows)
{
    __shared__ float sWs[32], sWi[32], sWr[32], sWb[32];   // W1 SoA + b1 (staging)
    __shared__ unsigned sOutP[4][64 * 15];   // per-wave fp16 output staging, stride 15 (pad)

    const int tid  = threadIdx.x;
    const int lane = tid & 63;
    const int wid  = tid >> 6;
    const int g    = lane >> 4;    // lane group = k-chunk (k = 8g..8g+7); own tile = g
    const int c15  = lane & 15;    // MFMA col = data row within a 16-row tile

    if (tid < 32) {
        sWs[tid] = W1[tid];
        sWi[tid] = W1[32 + tid];
        sWr[tid] = W1[64 + tid];
        sWb[tid] = b1[tid];
    }
    __syncthreads();

    // This lane's 8 W1 columns as packed fp16 even/odd pairs (RNE, setup-only)
    unsigned wps[4], wpi[4], wpr[4], wpb[4];
    #pragma unroll
    for (int p = 0; p < 4; ++p) {
        const int k0 = g*8 + 2*p;
        half2t a, b, c, d;
        a[0] = (_Float16)sWs[k0]; a[1] = (_Float16)sWs[k0+1];
        b[0] = (_Float16)sWi[k0]; b[1] = (_Float16)sWi[k0+1];
        c[0] = (_Float16)sWr[k0]; c[1] = (_Float16)sWr[k0+1];
        d[0] = (_Float16)sWb[k0]; d[1] = (_Float16)sWb[k0+1];
        wps[p] = __builtin_bit_cast(unsigned, a);
        wpi[p] = __builtin_bit_cast(unsigned, b);
        wpr[p] = __builtin_bit_cast(unsigned, c);
        wpb[p] = __builtin_bit_cast(unsigned, d);
    }

    // Persistent A-frags: W2 fp16 hi + lo residual. lane: A[out=c15][k=8g+j] = W2[k][c15]
    half8 ahi, alo;
    {
        u32x4 uh, ul;
        #pragma unroll
        for (int jj = 0; jj < 4; ++jj) {
            const float we = W2[(g*8 + 2*jj    )*16 + c15];
            const float wo = W2[(g*8 + 2*jj + 1)*16 + c15];
            half2t hh; hh[0] = (_Float16)we; hh[1] = (_Float16)wo;       // RNE
            half2t hl; hl[0] = (_Float16)(we - (float)hh[0]);
            hl[1] = (_Float16)(wo - (float)hh[1]);
            uh[jj] = __builtin_bit_cast(unsigned, hh);
            ul[jj] = __builtin_bit_cast(unsigned, hl);
        }
        ahi = __builtin_bit_cast(half8, uh);
        alo = __builtin_bit_cast(half8, ul);
    }
    const f32x4 b2f = *reinterpret_cast<const f32x4*>(b2 + g*4);   // C-init
    const f32x4 w3f = *reinterpret_cast<const f32x4*>(W3 + g*4);   // outs 4g..4g+3, fp32
    const float b3v = b3[0];

    const int row = blockIdx.x * 256 + tid;
    if (row >= nrows) return;   // never taken at B=2^20 (wave stays intact)

    const float* p = inputs + ((long)row * 8 + 7) * 3;
    float s  = p[0];
    float iv = p[1];
    float r  = p[2];
    const float rcpN = 1.0f / (s + iv + r);   // N conserved by SIR update

    // bpermute byte-addresses: tile m pulls from lane 16m + c15 (per-lane constant)
    const int adr0 = (c15     ) << 2;
    const int adr1 = (c15 + 16) << 2;
    const int adr2 = (c15 + 32) << 2;
    const int adr3 = (c15 + 48) << 2;

    const bool bt0 = (g & 1) != 0;   // group bit0 / bit1 (lane-constant)
    const bool bt1 = (g & 2) != 0;

    // one tile: packed-fp16 L1 from pre-splatted state words, 2 MFMA, fp32 L3 partial
    auto tile = [&](int ws, int wi, int wr) -> float {
        u32x4 ub;
        #pragma unroll
        for (int pp = 0; pp < 4; ++pp) {
            unsigned h = pk_fma((unsigned)ws, wps[pp], wpb[pp]);
            h = pk_fma((unsigned)wi, wpi[pp], h);
            h = pk_fma((unsigned)wr, wpr[pp], h);
            h = pk_max(h, 0u);
            ub[pp] = h;   // this IS the B-frag word {h1[k even], h1[k odd]}
        }
        const half8 bh = __builtin_bit_cast(half8, ub);
        f32x4 acc = __builtin_amdgcn_mfma_f32_16x16x32_f16(ahi, bh, b2f, 0, 0, 0);
        acc = __builtin_amdgcn_mfma_f32_16x16x32_f16(alo, bh, acc, 0, 0, 0);
        float pz = fmaxf(acc[0], 0.0f) * w3f[0];
        pz = fmaf(fmaxf(acc[1], 0.0f), w3f[1], pz);
        pz = fmaf(fmaxf(acc[2], 0.0f), w3f[2], pz);
        pz = fmaf(fmaxf(acc[3], 0.0f), w3f[3], pz);
        return pz;
    };

    auto step = [&]() -> float {
        // publish state pre-splatted as 3 packed-fp16 words; gather via ds_bpermute
        const int us = __builtin_bit_cast(int, __builtin_amdgcn_cvt_pkrtz(s, s));
        const int ui = __builtin_bit_cast(int, __builtin_amdgcn_cvt_pkrtz(iv, iv));
        const int ur = __builtin_bit_cast(int, __builtin_amdgcn_cvt_pkrtz(r, r));

        const float pz0 = tile(__builtin_amdgcn_ds_bpermute(adr0, us),
                               __builtin_amdgcn_ds_bpermute(adr0, ui),
                               __builtin_amdgcn_ds_bpermute(adr0, ur));
        const float pz1 = tile(__builtin_amdgcn_ds_bpermute(adr1, us),
                               __builtin_amdgcn_ds_bpermute(adr1, ui),
                               __builtin_amdgcn_ds_bpermute(adr1, ur));
        const float pz2 = tile(__builtin_amdgcn_ds_bpermute(adr2, us),
                               __builtin_amdgcn_ds_bpermute(adr2, ui),
                               __builtin_amdgcn_ds_bpermute(adr2, ur));
        const float pz3 = tile(__builtin_amdgcn_ds_bpermute(adr3, us),
                               __builtin_amdgcn_ds_bpermute(adr3, ui),
                               __builtin_amdgcn_ds_bpermute(adr3, ur));

        // dual-column butterfly reduce (bit-identical add tree to the full-sum version)
        const float colA  = bt1 ? pz3 : pz1;   // tile (bt1, 1)
        const float colB  = bt1 ? pz2 : pz0;   // tile (bt1, 0)
        const float colA2 = bt1 ? pz1 : pz3;   // tile (!bt1, 1)
        const float colB2 = bt1 ? pz0 : pz2;   // tile (!bt1, 0)
        const float Y  = bt0 ? colA  : colB;   // own tile g
        const float X  = bt0 ? colB  : colA;   // tile g^1 (what xor-16 partner needs)
        const float Y2 = bt0 ? colA2 : colB2;  // tile g^2
        const float X2 = bt0 ? colB2 : colA2;  // tile g^3
        const float u_own = Y  + __shfl_xor(X,  16, 64);  // groups {g,g^1} of tile g
        const float u_alt = Y2 + __shfl_xor(X2, 16, 64);  // groups {g,g^1} of tile g^2
        const float zb = (u_own + __shfl_xor(u_alt, 32, 64)) + b3v;

        // softplus (stable): max(z,0) + ln2*log2(1 + exp2(-|z|*log2e))
        const float t = __builtin_amdgcn_exp2f(-fabsf(zb) * 1.44269504088896341f);
        const float beta = fmaxf(zb, 0.0f) + 0.69314718055994531f * __builtin_amdgcn_logf(1.0f + t);
        const float new_inf = beta * s * iv * rcpN;
        const float new_rec = GAMMA * iv;
        s  = s - new_inf;
        iv = iv + new_inf - new_rec;
        r  = r + new_rec;
        return iv;
    };

    // 28 steps; stage outputs as packed fp16 into padded [64][15]-dword layout
    unsigned* const sOutW = &sOutP[wid][0];
    #pragma unroll 1
    for (int tt = 0; tt < 7; ++tt) {
        const float o0 = step();
        const float o1 = step();
        const float o2 = step();
        const float o3 = step();
        const unsigned pk0 = __builtin_bit_cast(unsigned, __builtin_amdgcn_cvt_pkrtz(o0, o1));
        const unsigned pk1 = __builtin_bit_cast(unsigned, __builtin_amdgcn_cvt_pkrtz(o2, o3));
        sOutW[lane * 15 + 2*tt]     = pk0;
        sOutW[lane * 15 + 2*tt + 1] = pk1;
    }

    // coalesced writeback: wave's 64 rows = 1792 contiguous floats in `out`
    const long gbase = (long)(blockIdx.x * 256 + wid * 64) * HORIZON;
    #pragma unroll
    for (int t = 0; t < 7; ++t) {
        const int e4 = t * 256 + lane * 4;   // float index within wave block (mult of 4)
        const int rr = e4 / 28;              // row; 28 % 4 == 0 -> float4 never crosses rows
        const int cc = e4 % 28;              // 0,4,...,24
        const unsigned d0 = sOutW[rr * 15 + (cc >> 1)];
        const unsigned d1 = sOutW[rr * 15 + (cc >> 1) + 1];
        const half2t h0 = __builtin_bit_cast(half2t, d0);
        const half2t h1 = __builtin_bit_cast(half2t, d1);
        f32x4 v;
        v[0] = (float)h0[0]; v[1] = (float)h0[1];
        v[2] = (float)h1[0]; v[3] = (float)h1[1];
        *reinterpret_cast<f32x4*>(out + gbase + e4) = v;
    }
}

extern "C" void kernel_launch(void* const* d_in, const int* in_sizes, int n_in,
                              void* d_out, int out_size, void* d_ws, size_t ws_size,
                              hipStream_t stream) {
    const float* inputs = (const float*)d_in[0];
    const float* W1 = (const float*)d_in[1];
    const float* b1 = (const float*)d_in[2];
    const float* W2 = (const float*)d_in[3];
    const float* b2 = (const float*)d_in[4];
    const float* W3 = (const float*)d_in[5];
    const float* b3 = (const float*)d_in[6];
    float* out = (float*)d_out;

    const int nrows = in_sizes[0] / 24;   // (B, 8, 3) fp32
    const int grid = (nrows + 255) / 256;
    sir_kernel<<<grid, 256, 0, stream>>>(inputs, W1, b1, W2, b2, W3, b3, out, nrows);
}

// Round 19
// 150.213 us; speedup vs baseline: 1.0352x; 1.0021x over previous
//
#include <hip/hip_runtime.h>

#define HORIZON 28
#define GAMMA 0.1f

typedef __attribute__((ext_vector_type(8))) _Float16 half8;   // MFMA A/B frag (4 VGPR)
typedef __attribute__((ext_vector_type(2))) _Float16 half2t;
typedef __attribute__((ext_vector_type(4))) float f32x4;      // MFMA C/D frag
typedef __attribute__((ext_vector_type(4))) unsigned int u32x4;

// guaranteed-packed fp16 ops (VOP3P), register-only so the scheduler can move them
__device__ __forceinline__ unsigned pk_fma(unsigned a, unsigned b, unsigned c) {
    unsigned d;
    asm("v_pk_fma_f16 %0, %1, %2, %3" : "=v"(d) : "v"(a), "v"(b), "v"(c));
    return d;
}
__device__ __forceinline__ unsigned pk_max(unsigned a, unsigned b) {
    unsigned d;
    asm("v_pk_max_f16 %0, %1, %2" : "=v"(d) : "v"(a), "v"(b));
    return d;
}
// butterfly xor-16 across the wave (BitMode swizzle; xor-16 stays within 32-lane halves)
__device__ __forceinline__ float swz16(float v) {
    return __builtin_bit_cast(float,
        __builtin_amdgcn_ds_swizzle(__builtin_bit_cast(int, v), 0x401F));
}

__global__ void __launch_bounds__(256) sir_kernel(
    const float* __restrict__ inputs,
    const float* __restrict__ W1,
    const float* __restrict__ b1,
    const float* __restrict__ W2,
    const float* __restrict__ b2,
    const float* __restrict__ W3,
    const float* __restrict__ b3,
    float* __restrict__ out,
    int nrows)
{
    __shared__ float sWs[32], sWi[32], sWr[32], sWb[32];   // W1 SoA + b1 (staging)
    __shared__ unsigned sOutP[4][64 * 15];   // per-wave fp16 output staging, stride 15 (pad)

    const int tid  = threadIdx.x;
    const int lane = tid & 63;
    const int wid  = tid >> 6;
    const int g    = lane >> 4;    // lane group = k-chunk (k = 8g..8g+7); own tile = g
    const int c15  = lane & 15;    // MFMA col = data row within a 16-row tile

    if (tid < 32) {
        sWs[tid] = W1[tid];
        sWi[tid] = W1[32 + tid];
        sWr[tid] = W1[64 + tid];
        sWb[tid] = b1[tid];
    }
    __syncthreads();

    // This lane's 8 W1 columns as packed fp16 even/odd pairs (RNE, setup-only)
    unsigned wps[4], wpi[4], wpr[4], wpb[4];
    #pragma unroll
    for (int p = 0; p < 4; ++p) {
        const int k0 = g*8 + 2*p;
        half2t a, b, c, d;
        a[0] = (_Float16)sWs[k0]; a[1] = (_Float16)sWs[k0+1];
        b[0] = (_Float16)sWi[k0]; b[1] = (_Float16)sWi[k0+1];
        c[0] = (_Float16)sWr[k0]; c[1] = (_Float16)sWr[k0+1];
        d[0] = (_Float16)sWb[k0]; d[1] = (_Float16)sWb[k0+1];
        wps[p] = __builtin_bit_cast(unsigned, a);
        wpi[p] = __builtin_bit_cast(unsigned, b);
        wpr[p] = __builtin_bit_cast(unsigned, c);
        wpb[p] = __builtin_bit_cast(unsigned, d);
    }

    // Persistent A-frags: W2 fp16 hi + lo residual. lane: A[out=c15][k=8g+j] = W2[k][c15]
    half8 ahi, alo;
    {
        u32x4 uh, ul;
        #pragma unroll
        for (int jj = 0; jj < 4; ++jj) {
            const float we = W2[(g*8 + 2*jj    )*16 + c15];
            const float wo = W2[(g*8 + 2*jj + 1)*16 + c15];
            half2t hh; hh[0] = (_Float16)we; hh[1] = (_Float16)wo;       // RNE
            half2t hl; hl[0] = (_Float16)(we - (float)hh[0]);
            hl[1] = (_Float16)(wo - (float)hh[1]);
            uh[jj] = __builtin_bit_cast(unsigned, hh);
            ul[jj] = __builtin_bit_cast(unsigned, hl);
        }
        ahi = __builtin_bit_cast(half8, uh);
        alo = __builtin_bit_cast(half8, ul);
    }
    const f32x4 b2f = *reinterpret_cast<const f32x4*>(b2 + g*4);   // C-init
    const f32x4 w3f = *reinterpret_cast<const f32x4*>(W3 + g*4);   // outs 4g..4g+3, fp32
    const float b3v = b3[0];

    const int row = blockIdx.x * 256 + tid;
    if (row >= nrows) return;   // never taken at B=2^20 (wave stays intact)

    const float* p = inputs + ((long)row * 8 + 7) * 3;
    float s  = p[0];
    float iv = p[1];
    float r  = p[2];
    const float rcpN = 1.0f / (s + iv + r);   // N conserved by SIR update

    // bpermute byte-addresses: tile m pulls from lane 16m + c15 (per-lane constant)
    const int adr0 = (c15     ) << 2;
    const int adr1 = (c15 + 16) << 2;
    const int adr2 = (c15 + 32) << 2;
    const int adr3 = (c15 + 48) << 2;

    const bool bt0 = (g & 1) != 0;   // group bit0 / bit1 (lane-constant)
    const bool bt1 = (g & 2) != 0;

    // one tile: packed-fp16 L1 from pre-splatted state words, 2 MFMA, fp32 L3 partial
    auto tile = [&](int ws, int wi, int wr) -> float {
        u32x4 ub;
        #pragma unroll
        for (int pp = 0; pp < 4; ++pp) {
            unsigned h = pk_fma((unsigned)ws, wps[pp], wpb[pp]);
            h = pk_fma((unsigned)wi, wpi[pp], h);
            h = pk_fma((unsigned)wr, wpr[pp], h);
            h = pk_max(h, 0u);
            ub[pp] = h;   // this IS the B-frag word {h1[k even], h1[k odd]}
        }
        const half8 bh = __builtin_bit_cast(half8, ub);
        f32x4 acc = __builtin_amdgcn_mfma_f32_16x16x32_f16(ahi, bh, b2f, 0, 0, 0);
        acc = __builtin_amdgcn_mfma_f32_16x16x32_f16(alo, bh, acc, 0, 0, 0);
        float pz = fmaxf(acc[0], 0.0f) * w3f[0];
        pz = fmaf(fmaxf(acc[1], 0.0f), w3f[1], pz);
        pz = fmaf(fmaxf(acc[2], 0.0f), w3f[2], pz);
        pz = fmaf(fmaxf(acc[3], 0.0f), w3f[3], pz);
        return pz;
    };

    auto step = [&]() -> float {
        // publish state pre-splatted as 3 packed-fp16 words
        const int us = __builtin_bit_cast(int, __builtin_amdgcn_cvt_pkrtz(s, s));
        const int ui = __builtin_bit_cast(int, __builtin_amdgcn_cvt_pkrtz(iv, iv));
        const int ur = __builtin_bit_cast(int, __builtin_amdgcn_cvt_pkrtz(r, r));

        // software-pipelined gathers: tile m+1's bpermutes issued before tile m is consumed
        int s0 = __builtin_amdgcn_ds_bpermute(adr0, us);
        int i0 = __builtin_amdgcn_ds_bpermute(adr0, ui);
        int r0 = __builtin_amdgcn_ds_bpermute(adr0, ur);
        int s1 = __builtin_amdgcn_ds_bpermute(adr1, us);
        int i1 = __builtin_amdgcn_ds_bpermute(adr1, ui);
        int r1 = __builtin_amdgcn_ds_bpermute(adr1, ur);
        const float pz0 = tile(s0, i0, r0);
        int s2 = __builtin_amdgcn_ds_bpermute(adr2, us);
        int i2 = __builtin_amdgcn_ds_bpermute(adr2, ui);
        int r2 = __builtin_amdgcn_ds_bpermute(adr2, ur);
        const float pz1 = tile(s1, i1, r1);
        int s3 = __builtin_amdgcn_ds_bpermute(adr3, us);
        int i3 = __builtin_amdgcn_ds_bpermute(adr3, ui);
        int r3 = __builtin_amdgcn_ds_bpermute(adr3, ur);
        const float pz2 = tile(s2, i2, r2);
        const float pz3 = tile(s3, i3, r3);

        // dual-column butterfly reduce (bit-identical add tree to the full-sum version)
        const float colA  = bt1 ? pz3 : pz1;   // tile (bt1, 1)
        const float colB  = bt1 ? pz2 : pz0;   // tile (bt1, 0)
        const float colA2 = bt1 ? pz1 : pz3;   // tile (!bt1, 1)
        const float colB2 = bt1 ? pz0 : pz2;   // tile (!bt1, 0)
        const float Y  = bt0 ? colA  : colB;   // own tile g
        const float X  = bt0 ? colB  : colA;   // tile g^1 (what xor-16 partner needs)
        const float Y2 = bt0 ? colA2 : colB2;  // tile g^2
        const float X2 = bt0 ? colB2 : colA2;  // tile g^3
        const float u_own = Y  + swz16(X);     // groups {g,g^1} of tile g
        const float u_alt = Y2 + swz16(X2);    // groups {g,g^1} of tile g^2
        const float zb = (u_own + __shfl_xor(u_alt, 32, 64)) + b3v;

        // softplus (stable): max(z,0) + ln2*log2(1 + exp2(-|z|*log2e))
        const float t = __builtin_amdgcn_exp2f(-fabsf(zb) * 1.44269504088896341f);
        const float beta = fmaxf(zb, 0.0f) + 0.69314718055994531f * __builtin_amdgcn_logf(1.0f + t);
        const float new_inf = beta * s * iv * rcpN;
        const float new_rec = GAMMA * iv;
        s  = s - new_inf;
        iv = iv + new_inf - new_rec;
        r  = r + new_rec;
        return iv;
    };

    // 28 steps; stage outputs as packed fp16 into padded [64][15]-dword layout
    unsigned* const sOutW = &sOutP[wid][0];
    #pragma unroll 1
    for (int tt = 0; tt < 7; ++tt) {
        const float o0 = step();
        const float o1 = step();
        const float o2 = step();
        const float o3 = step();
        const unsigned pk0 = __builtin_bit_cast(unsigned, __builtin_amdgcn_cvt_pkrtz(o0, o1));
        const unsigned pk1 = __builtin_bit_cast(unsigned, __builtin_amdgcn_cvt_pkrtz(o2, o3));
        sOutW[lane * 15 + 2*tt]     = pk0;
        sOutW[lane * 15 + 2*tt + 1] = pk1;
    }

    // coalesced writeback: wave's 64 rows = 1792 contiguous floats in `out`
    const long gbase = (long)(blockIdx.x * 256 + wid * 64) * HORIZON;
    #pragma unroll
    for (int t = 0; t < 7; ++t) {
        const int e4 = t * 256 + lane * 4;   // float index within wave block (mult of 4)
        const int rr = e4 / 28;              // row; 28 % 4 == 0 -> float4 never crosses rows
        const int cc = e4 % 28;              // 0,4,...,24
        const unsigned d0 = sOutW[rr * 15 + (cc >> 1)];
        const unsigned d1 = sOutW[rr * 15 + (cc >> 1) + 1];
        const half2t h0 = __builtin_bit_cast(half2t, d0);
        const half2t h1 = __builtin_bit_cast(half2t, d1);
        f32x4 v;
        v[0] = (float)h0[0]; v[1] = (float)h0[1];
        v[2] = (float)h1[0]; v[3] = (float)h1[1];
        *reinterpret_cast<f32x4*>(out + gbase + e4) = v;
    }
}

extern "C" void kernel_launch(void* const* d_in, const int* in_sizes, int n_in,
                              void* d_out, int out_size, void* d_ws, size_t ws_size,
                              hipStream_t stream) {
    const float* inputs = (const float*)d_in[0];
    const float* W1 = (const float*)d_in[1];
    const float* b1 = (const float*)d_in[2];
    const float* W2 = (const float*)d_in[3];
    const float* b2 = (const float*)d_in[4];
    const float* W3 = (const float*)d_in[5];
    const float* b3 = (const float*)d_in[6];
    float* out = (float*)d_out;

    const int nrows = in_sizes[0] / 24;   // (B, 8, 3) fp32
    const int grid = (nrows + 255) / 256;
    sir_kernel<<<grid, 256, 0, stream>>>(inputs, W1, b1, W2, b2, W3, b3, out, nrows);
}